// Round 4
// baseline (1028.511 us; speedup 1.0000x reference)
//
#include <hip/hip_runtime.h>

#define TSEQ 512
#define HID  64
#define NTH  512    // 8 waves: 0-3 layer0, 4-7 layer1
// Block handles 16 batch = 2 independent tiles of 8 (MFMA N-cols duplicated,
// activations j-split across lane halves). Two tiles per wave = 2 independent
// dependency chains -> intra-wave latency hiding at fixed 2 waves/SIMD.

typedef __attribute__((ext_vector_type(8))) short short8;
typedef __attribute__((ext_vector_type(4))) float f32x4;
typedef __attribute__((ext_vector_type(4))) unsigned int u32x4;

__device__ __forceinline__ float fsig(float x) {
    float e = __builtin_amdgcn_exp2f(x * -1.44269504088896340736f);
    return __builtin_amdgcn_rcpf(1.0f + e);
}
__device__ __forceinline__ float ftanh(float x) {
    float e = __builtin_amdgcn_exp2f(x * 2.88539008177792681472f);
    return 1.0f - 2.0f * __builtin_amdgcn_rcpf(1.0f + e);
}
__device__ __forceinline__ unsigned rne16(float f) {
    unsigned u = __builtin_bit_cast(unsigned, f);
    return ((u + 0x7fffu + ((u >> 16) & 1u)) >> 16) & 0xffffu;
}
// pack two f32 into one hi-plane word (trunc-bf16) and one lo-plane word (rne residual)
__device__ __forceinline__ void packPair(float a, float b, unsigned* hw, unsigned* lw) {
    unsigned ua = __builtin_bit_cast(unsigned, a), ub = __builtin_bit_cast(unsigned, b);
    unsigned ha = ua & 0xffff0000u, hb = ub & 0xffff0000u;
    *hw = (ha >> 16) | hb;
    *lw = rne16(a - __builtin_bit_cast(float, ha)) |
          (rne16(b - __builtin_bit_cast(float, hb)) << 16);
}
// split 8 f32 weights into hi/lo bf16x8 fragments (element e <-> k-offset e)
__device__ __forceinline__ void packA(const float w8[8], short8* fhi, short8* flo) {
    unsigned hw[8], lw[8];
    #pragma unroll
    for (int e = 0; e < 8; ++e) {
        unsigned u  = __builtin_bit_cast(unsigned, w8[e]);
        unsigned hb = u & 0xffff0000u;
        hw[e] = u >> 16;
        lw[e] = rne16(w8[e] - __builtin_bit_cast(float, hb));
    }
    u32x4 H = { hw[0] | (hw[1] << 16), hw[2] | (hw[3] << 16),
                hw[4] | (hw[5] << 16), hw[6] | (hw[7] << 16) };
    u32x4 L = { lw[0] | (lw[1] << 16), lw[2] | (lw[3] << 16),
                lw[4] | (lw[5] << 16), lw[6] | (lw[7] << 16) };
    *fhi = __builtin_bit_cast(short8, H);
    *flo = __builtin_bit_cast(short8, L);
}

#define MFMA(a, b, c) __builtin_amdgcn_mfma_f32_16x16x32_bf16((a), (b), (c), 0, 0, 0)

// plane word address: logical u32 word q (0..31) of row n (0..7),
// diagonal granule swizzle keeps b128 reads/writes at the bank minimum
__device__ __forceinline__ int pw(int n, int q) {
    return n * 32 + ((((q >> 2) + n) & 7) << 2) + (q & 3);
}
__device__ __forceinline__ short8 ld128(const unsigned* plane, int n, int q0) {
    int off = n * 32 + ((((q0 >> 2) + n) & 7) << 2);
    return __builtin_bit_cast(short8, *(const u32x4*)(plane + off));
}
__device__ __forceinline__ float actstep(float ai, float af, float ag, float ao, float* c) {
    float it = fsig(ai), ft = fsig(af), gt = ftanh(ag), ot = fsig(ao);
    *c = ft * *c + it * gt;
    return ot * ftanh(*c);
}

__global__ __launch_bounds__(NTH, 2)
void lstm2_mfma(const float* __restrict__ x,
                const float* __restrict__ W_ih0, const float* __restrict__ W_hh0,
                const float* __restrict__ b_ih0, const float* __restrict__ b_hh0,
                const float* __restrict__ W_ih1, const float* __restrict__ W_hh1,
                const float* __restrict__ b_ih1, const float* __restrict__ b_hh1,
                const float* __restrict__ W_fc,  const float* __restrict__ b_fc,
                float* __restrict__ out)
{
    const int tid  = threadIdx.x;
    const int lane = tid & 63;
    const int wv   = tid >> 6;        // 0-3: layer0, 4-7: layer1
    const int rl   = lane & 15;       // MFMA row/col index
    const int g    = lane >> 4;       // k-group 0..3
    const int n    = rl & 7;          // batch col within tile (cols 8-15 duplicate)
    const int hi8  = (rl >> 3) & 1;   // j-split: lanes rl<8 do j=0,1; rl>=8 do j=2,3
    const int b0   = blockIdx.x * 16;

    // hi/lo bf16 planes, [tile][parity][8 rows x 32 words]
    __shared__ unsigned h0hi[2][2][256], h0lo[2][2][256];
    __shared__ unsigned h1hi[2][2][256], h1lo[2][2][256];
    __shared__ unsigned xhi[2][2][16],  xlo[2][2][16];
    __shared__ float fcl[64][16];

    for (int idx = tid; idx < 1024; idx += NTH) {
        ((unsigned*)h0hi)[idx] = 0u; ((unsigned*)h0lo)[idx] = 0u;
        ((unsigned*)h1hi)[idx] = 0u; ((unsigned*)h1lo)[idx] = 0u;
    }
    // stage x[0] into parity 0
    if (tid < 16) {
        f32x4 xv = *(const f32x4*)(x + ((size_t)(b0 + tid) * TSEQ) * 4);
        int T = tid >> 3, nn = tid & 7;
        unsigned hw0, lw0, hw1, lw1;
        packPair(xv.x, xv.y, &hw0, &lw0);
        packPair(xv.z, xv.w, &hw1, &lw1);
        xhi[T][0][nn*2+0] = hw0; xhi[T][0][nn*2+1] = hw1;
        xlo[T][0][nn*2+0] = lw0; xlo[T][0][nn*2+1] = lw1;
    }
    __syncthreads();

    if (wv < 4) {
        // ======== LAYER 0: wave w owns u in [16w,16w+16) for all 4 gates ========
        const int w = wv;
        short8 A0[4][3][2];           // [gate][s][hi/lo]; s=0,1: W_hh0; s=2: W_ih0 (k0..3)
        f32x4  bias4[4];
        #pragma unroll
        for (int G = 0; G < 4; ++G) {
            const int row = 64*G + 16*w + rl;
            #pragma unroll
            for (int s = 0; s < 3; ++s) {
                float w8[8];
                if (s < 2) {
                    const float* src = W_hh0 + row*64 + s*32 + g*8;
                    #pragma unroll
                    for (int e = 0; e < 8; ++e) w8[e] = src[e];
                } else {
                    #pragma unroll
                    for (int e = 0; e < 8; ++e) w8[e] = 0.f;
                    if (g == 0) {
                        #pragma unroll
                        for (int e = 0; e < 4; ++e) w8[e] = W_ih0[row*4 + e];
                    }
                }
                packA(w8, &A0[G][s][0], &A0[G][s][1]);
            }
            const int rb = 64*G + 16*w + 4*g;
            bias4[G].x = b_ih0[rb+0] + b_hh0[rb+0];
            bias4[G].y = b_ih0[rb+1] + b_hh0[rb+1];
            bias4[G].z = b_ih0[rb+2] + b_hh0[rb+2];
            bias4[G].w = b_ih0[rb+3] + b_hh0[rb+3];
        }
        float cst[2][2] = {{0.f,0.f},{0.f,0.f}};   // [tile][jj]
        const int q  = 8*w + 2*g + hi8;            // write word index (u-pair)

        for (int i = 0; i <= TSEQ; ++i) {
            if (i < TSEQ) {
                const int p = i & 1;
                f32x4 xf;
                const bool doX = (w == 0) && (lane < 16) && (i + 1 < TSEQ);
                if (doX) xf = *(const f32x4*)(x + ((size_t)(b0 + lane) * TSEQ + (i+1)) * 4);

                short8 Bh[2][2], Bl[2][2], Bxh[2], Bxl[2];
                #pragma unroll
                for (int T = 0; T < 2; ++T) {
                    #pragma unroll
                    for (int s = 0; s < 2; ++s) {
                        Bh[T][s] = ld128(h0hi[T][p], n, 16*s + 4*g);
                        Bl[T][s] = ld128(h0lo[T][p], n, 16*s + 4*g);
                    }
                    u32x4 th = { xhi[T][p][n*2], xhi[T][p][n*2+1], 0u, 0u };
                    u32x4 tl = { xlo[T][p][n*2], xlo[T][p][n*2+1], 0u, 0u };
                    Bxh[T] = __builtin_bit_cast(short8, th);
                    Bxl[T] = __builtin_bit_cast(short8, tl);
                }

                f32x4 acc[2][4];
                __builtin_amdgcn_s_setprio(1);
                #pragma unroll
                for (int G = 0; G < 4; ++G) {
                    #pragma unroll
                    for (int T = 0; T < 2; ++T) {
                        acc[T][G] = MFMA(A0[G][0][0], Bh[T][0], bias4[G]);
                        acc[T][G] = MFMA(A0[G][0][0], Bl[T][0], acc[T][G]);
                        acc[T][G] = MFMA(A0[G][0][1], Bh[T][0], acc[T][G]);
                        acc[T][G] = MFMA(A0[G][1][0], Bh[T][1], acc[T][G]);
                        acc[T][G] = MFMA(A0[G][1][0], Bl[T][1], acc[T][G]);
                        acc[T][G] = MFMA(A0[G][1][1], Bh[T][1], acc[T][G]);
                        acc[T][G] = MFMA(A0[G][2][0], Bxh[T],  acc[T][G]);
                        acc[T][G] = MFMA(A0[G][2][0], Bxl[T],  acc[T][G]);
                        acc[T][G] = MFMA(A0[G][2][1], Bxh[T],  acc[T][G]);
                    }
                }
                __builtin_amdgcn_s_setprio(0);

                #pragma unroll
                for (int T = 0; T < 2; ++T) {
                    float a0[4], a1[4];
                    #pragma unroll
                    for (int G = 0; G < 4; ++G) {
                        a0[G] = hi8 ? acc[T][G].z : acc[T][G].x;
                        a1[G] = hi8 ? acc[T][G].w : acc[T][G].y;
                    }
                    float hv0 = actstep(a0[0], a0[1], a0[2], a0[3], &cst[T][0]);
                    float hv1 = actstep(a1[0], a1[1], a1[2], a1[3], &cst[T][1]);
                    unsigned hw, lw;
                    packPair(hv0, hv1, &hw, &lw);
                    const int off = pw(n, q);
                    h0hi[T][p^1][off] = hw;
                    h0lo[T][p^1][off] = lw;
                }
                if (doX) {
                    int T = lane >> 3, nn = lane & 7;
                    unsigned hw0, lw0, hw1, lw1;
                    packPair(xf.x, xf.y, &hw0, &lw0);
                    packPair(xf.z, xf.w, &hw1, &lw1);
                    xhi[T][p^1][nn*2+0] = hw0; xhi[T][p^1][nn*2+1] = hw1;
                    xlo[T][p^1][nn*2+0] = lw0; xlo[T][p^1][nn*2+1] = lw1;
                }
            }
            __syncthreads();
        }
    } else {
        // ======== LAYER 1 (1-step skew): iter i computes t=i-1 ========
        const int w = wv - 4;
        short8 A1[4][4][2];           // s=0,1: W_ih1 (vs h0); s=2,3: W_hh1 (vs h1)
        f32x4  bias4[4];
        #pragma unroll
        for (int G = 0; G < 4; ++G) {
            const int row = 64*G + 16*w + rl;
            #pragma unroll
            for (int s = 0; s < 4; ++s) {
                float w8[8];
                const float* src = (s < 2) ? (W_ih1 + row*64 + s*32 + g*8)
                                           : (W_hh1 + row*64 + (s-2)*32 + g*8);
                #pragma unroll
                for (int e = 0; e < 8; ++e) w8[e] = src[e];
                packA(w8, &A1[G][s][0], &A1[G][s][1]);
            }
            const int rb = 64*G + 16*w + 4*g;
            bias4[G].x = b_ih1[rb+0] + b_hh1[rb+0];
            bias4[G].y = b_ih1[rb+1] + b_hh1[rb+1];
            bias4[G].z = b_ih1[rb+2] + b_hh1[rb+2];
            bias4[G].w = b_ih1[rb+3] + b_hh1[rb+3];
        }
        float cst[2][2] = {{0.f,0.f},{0.f,0.f}};
        const int q  = 8*w + 2*g + hi8;
        const int u0 = 16*w + 4*g + 2*hi8;         // first owned unit row

        for (int i = 0; i <= TSEQ; ++i) {
            if (i > 0) {
                const int p = i & 1;
                short8 Bh[2][4], Bl[2][4];
                #pragma unroll
                for (int T = 0; T < 2; ++T) {
                    #pragma unroll
                    for (int s = 0; s < 2; ++s) {
                        Bh[T][s]   = ld128(h0hi[T][p], n, 16*s + 4*g);
                        Bl[T][s]   = ld128(h0lo[T][p], n, 16*s + 4*g);
                        Bh[T][s+2] = ld128(h1hi[T][p], n, 16*s + 4*g);
                        Bl[T][s+2] = ld128(h1lo[T][p], n, 16*s + 4*g);
                    }
                }
                f32x4 acc[2][4];
                __builtin_amdgcn_s_setprio(1);
                #pragma unroll
                for (int G = 0; G < 4; ++G) {
                    #pragma unroll
                    for (int T = 0; T < 2; ++T) {
                        acc[T][G] = MFMA(A1[G][0][0], Bh[T][0], bias4[G]);
                        #pragma unroll
                        for (int s = 0; s < 4; ++s) {
                            if (s > 0) acc[T][G] = MFMA(A1[G][s][0], Bh[T][s], acc[T][G]);
                            acc[T][G] = MFMA(A1[G][s][0], Bl[T][s], acc[T][G]);
                            acc[T][G] = MFMA(A1[G][s][1], Bh[T][s], acc[T][G]);
                        }
                    }
                }
                __builtin_amdgcn_s_setprio(0);

                #pragma unroll
                for (int T = 0; T < 2; ++T) {
                    float a0[4], a1[4];
                    #pragma unroll
                    for (int G = 0; G < 4; ++G) {
                        a0[G] = hi8 ? acc[T][G].z : acc[T][G].x;
                        a1[G] = hi8 ? acc[T][G].w : acc[T][G].y;
                    }
                    float hv0 = actstep(a0[0], a0[1], a0[2], a0[3], &cst[T][0]);
                    float hv1 = actstep(a1[0], a1[1], a1[2], a1[3], &cst[T][1]);
                    unsigned hw, lw;
                    packPair(hv0, hv1, &hw, &lw);
                    const int off = pw(n, q);
                    h1hi[T][p^1][off] = hw;
                    h1lo[T][p^1][off] = lw;
                    if (i == TSEQ) {
                        fcl[u0+0][T*8+n] = hv0;
                        fcl[u0+1][T*8+n] = hv1;
                    }
                }
            }
            __syncthreads();
        }
    }
    __syncthreads();

    // ---- FC: out[b] = h1_last[b,:] . W_fc + b_fc ----
    if (tid < 16) {
        float acc = b_fc[0];
        #pragma unroll 16
        for (int u = 0; u < 64; ++u) acc += fcl[u][tid] * W_fc[u];
        out[b0 + tid] = acc;
    }
}

extern "C" void kernel_launch(void* const* d_in, const int* in_sizes, int n_in,
                              void* d_out, int out_size, void* d_ws, size_t ws_size,
                              hipStream_t stream) {
    const float* x     = (const float*)d_in[0];
    const float* W_ih0 = (const float*)d_in[1];
    const float* W_hh0 = (const float*)d_in[2];
    const float* b_ih0 = (const float*)d_in[3];
    const float* b_hh0 = (const float*)d_in[4];
    const float* W_ih1 = (const float*)d_in[5];
    const float* W_hh1 = (const float*)d_in[6];
    const float* b_ih1 = (const float*)d_in[7];
    const float* b_hh1 = (const float*)d_in[8];
    const float* W_fc  = (const float*)d_in[9];
    const float* b_fc  = (const float*)d_in[10];
    float* out = (float*)d_out;

    dim3 grid(4096 / 16), block(NTH);
    hipLaunchKernelGGL(lstm2_mfma, grid, block, 0, stream,
                       x, W_ih0, W_hh0, b_ih0, b_hh0,
                       W_ih1, W_hh1, b_ih1, b_hh1, W_fc, b_fc, out);
}

// Round 5
// 627.843 us; speedup vs baseline: 1.6382x; 1.6382x over previous
//
#include <hip/hip_runtime.h>

#define TSEQ 512
#define HID  64
#define NTH  512    // 8 waves: 0-3 layer0, 4-7 layer1; 16 batch/block, 256 blocks = 1/CU

typedef __attribute__((ext_vector_type(8))) short short8;
typedef __attribute__((ext_vector_type(4))) float f32x4;
typedef __attribute__((ext_vector_type(4))) unsigned int u32x4;

__device__ __forceinline__ float fsig(float x) {
    float e = __builtin_amdgcn_exp2f(x * -1.44269504088896340736f);
    return __builtin_amdgcn_rcpf(1.0f + e);
}
__device__ __forceinline__ float ftanh(float x) {
    float e = __builtin_amdgcn_exp2f(x * 2.88539008177792681472f);
    return 1.0f - 2.0f * __builtin_amdgcn_rcpf(1.0f + e);
}
__device__ __forceinline__ unsigned rne16(float f) {
    unsigned u = __builtin_bit_cast(unsigned, f);
    return ((u + 0x7fffu + ((u >> 16) & 1u)) >> 16) & 0xffffu;
}
// pack two f32 into one hi-plane word (trunc-bf16 pair) + one lo-plane word (rne residual pair)
__device__ __forceinline__ void packPair(float a, float b, unsigned* hw, unsigned* lw) {
    unsigned ua = __builtin_bit_cast(unsigned, a), ub = __builtin_bit_cast(unsigned, b);
    unsigned ha = ua & 0xffff0000u, hb = ub & 0xffff0000u;
    *hw = (ha >> 16) | hb;
    *lw = rne16(a - __builtin_bit_cast(float, ha)) |
          (rne16(b - __builtin_bit_cast(float, hb)) << 16);
}
// split 8 f32 weights into hi/lo bf16x8 A-fragments (element e <-> k-offset e)
__device__ __forceinline__ void packA(const float w8[8], short8* fhi, short8* flo) {
    unsigned hw[8], lw[8];
    #pragma unroll
    for (int e = 0; e < 8; ++e) {
        unsigned u  = __builtin_bit_cast(unsigned, w8[e]);
        unsigned hb = u & 0xffff0000u;
        hw[e] = u >> 16;
        lw[e] = rne16(w8[e] - __builtin_bit_cast(float, hb));
    }
    u32x4 H = { hw[0] | (hw[1] << 16), hw[2] | (hw[3] << 16),
                hw[4] | (hw[5] << 16), hw[6] | (hw[7] << 16) };
    u32x4 L = { lw[0] | (lw[1] << 16), lw[2] | (lw[3] << 16),
                lw[4] | (lw[5] << 16), lw[6] | (lw[7] << 16) };
    *fhi = __builtin_bit_cast(short8, H);
    *flo = __builtin_bit_cast(short8, L);
}

#define MFMA(a, b, c) __builtin_amdgcn_mfma_f32_16x16x32_bf16((a), (b), (c), 0, 0, 0)

// plane: [16 n-rows][32 words]; diagonal granule swizzle (granule = 4 words = 16B)
// read b128 at logical words [q0, q0+4) of row n
__device__ __forceinline__ short8 ld128(const unsigned* plane, int n, int q0) {
    int off = n * 32 + ((((q0 >> 2) + n) & 7) << 2);
    return __builtin_bit_cast(short8, *(const u32x4*)(plane + off));
}
// word offset for b64 write at logical words q0 (even), q0+1 of row n
__device__ __forceinline__ int w64off(int n, int q0) {
    return n * 32 + ((((q0 >> 2) + n) & 7) << 2) + (q0 & 3);
}
__device__ __forceinline__ float actstep(float ai, float af, float ag, float ao, float* c) {
    float it = fsig(ai), ft = fsig(af), gt = ftanh(ag), ot = fsig(ao);
    *c = ft * *c + it * gt;
    return ot * ftanh(*c);
}

__global__ __launch_bounds__(NTH, 2)
void lstm2_mfma(const float* __restrict__ x,
                const float* __restrict__ W_ih0, const float* __restrict__ W_hh0,
                const float* __restrict__ b_ih0, const float* __restrict__ b_hh0,
                const float* __restrict__ W_ih1, const float* __restrict__ W_hh1,
                const float* __restrict__ b_ih1, const float* __restrict__ b_hh1,
                const float* __restrict__ W_fc,  const float* __restrict__ b_fc,
                float* __restrict__ out)
{
    const int tid  = threadIdx.x;
    const int lane = tid & 63;
    const int wv   = tid >> 6;        // 0-3: layer0, 4-7: layer1
    const int rl   = lane & 15;       // MFMA row/col index = batch col n
    const int g    = lane >> 4;       // k-group 0..3
    const int b0   = blockIdx.x * 16;

    // hi/lo bf16 planes: [parity][16 n x 32 words]
    __shared__ unsigned h0hi[2][512], h0lo[2][512];
    __shared__ unsigned h1hi[2][512], h1lo[2][512];
    __shared__ unsigned xhi[2][32],  xlo[2][32];   // [parity][16 n x 2 words]
    __shared__ float fcl[64 * 17];                 // padded 16->17

    for (int i2 = tid; i2 < 1024; i2 += NTH) {
        ((unsigned*)h0hi)[i2] = 0u; ((unsigned*)h0lo)[i2] = 0u;
        ((unsigned*)h1hi)[i2] = 0u; ((unsigned*)h1lo)[i2] = 0u;
    }
    // stage x[0] into parity 0
    if (tid < 16) {
        f32x4 xv = *(const f32x4*)(x + ((size_t)(b0 + tid) * TSEQ) * 4);
        unsigned hw0, lw0, hw1, lw1;
        packPair(xv.x, xv.y, &hw0, &lw0);
        packPair(xv.z, xv.w, &hw1, &lw1);
        xhi[0][tid*2+0] = hw0; xhi[0][tid*2+1] = hw1;
        xlo[0][tid*2+0] = lw0; xlo[0][tid*2+1] = lw1;
    }
    __syncthreads();

    if (wv < 4) {
        // ======== LAYER 0: wave w owns u in [16w,16w+16) for all 4 gates ========
        const int w = wv;
        short8 A0[4][3][2];           // [gate][s][hi/lo]; s=0,1: W_hh0; s=2: W_ih0 (k0..3)
        f32x4  bias4[4];
        #pragma unroll
        for (int G = 0; G < 4; ++G) {
            const int row = 64*G + 16*w + rl;
            #pragma unroll
            for (int s = 0; s < 3; ++s) {
                float w8[8];
                if (s < 2) {
                    const float* src = W_hh0 + row*64 + s*32 + g*8;
                    #pragma unroll
                    for (int e = 0; e < 8; ++e) w8[e] = src[e];
                } else {
                    #pragma unroll
                    for (int e = 0; e < 8; ++e) w8[e] = 0.f;
                    if (g == 0) {
                        #pragma unroll
                        for (int e = 0; e < 4; ++e) w8[e] = W_ih0[row*4 + e];
                    }
                }
                packA(w8, &A0[G][s][0], &A0[G][s][1]);
            }
            const int rb = 64*G + 16*w + 4*g;
            bias4[G].x = b_ih0[rb+0] + b_hh0[rb+0];
            bias4[G].y = b_ih0[rb+1] + b_hh0[rb+1];
            bias4[G].z = b_ih0[rb+2] + b_hh0[rb+2];
            bias4[G].w = b_ih0[rb+3] + b_hh0[rb+3];
        }
        float cst[4] = {0.f, 0.f, 0.f, 0.f};
        const int woff = w64off(rl, 8*w + 2*g);    // b64 write offset (u-pairs j01, j23)

        for (int i = 0; i <= TSEQ; ++i) {
            if (i < TSEQ) {
                const int p = i & 1;
                f32x4 xf;
                const bool doX = (w == 0) && (lane < 16) && (i + 1 < TSEQ);
                if (doX) xf = *(const f32x4*)(x + ((size_t)(b0 + lane) * TSEQ + (i+1)) * 4);

                // B fragments: direct plane reads, zero repack
                short8 Bh0 = ld128(h0hi[p], rl, 4*g);
                short8 Bl0 = ld128(h0lo[p], rl, 4*g);
                short8 Bh1 = ld128(h0hi[p], rl, 16 + 4*g);
                short8 Bl1 = ld128(h0lo[p], rl, 16 + 4*g);
                short8 Bxh, Bxl;
                {
                    uint2 a = *(const uint2*)&xhi[p][rl*2];
                    uint2 b = *(const uint2*)&xlo[p][rl*2];
                    u32x4 th = { a.x, a.y, 0u, 0u };
                    u32x4 tl = { b.x, b.y, 0u, 0u };
                    Bxh = __builtin_bit_cast(short8, th);
                    Bxl = __builtin_bit_cast(short8, tl);
                }

                f32x4 acc[4];
                __builtin_amdgcn_s_setprio(1);
                #pragma unroll
                for (int G = 0; G < 4; ++G) acc[G] = MFMA(A0[G][0][0], Bh0, bias4[G]);
                #pragma unroll
                for (int G = 0; G < 4; ++G) acc[G] = MFMA(A0[G][0][0], Bl0, acc[G]);
                #pragma unroll
                for (int G = 0; G < 4; ++G) acc[G] = MFMA(A0[G][0][1], Bh0, acc[G]);
                #pragma unroll
                for (int G = 0; G < 4; ++G) acc[G] = MFMA(A0[G][1][0], Bh1, acc[G]);
                #pragma unroll
                for (int G = 0; G < 4; ++G) acc[G] = MFMA(A0[G][1][0], Bl1, acc[G]);
                #pragma unroll
                for (int G = 0; G < 4; ++G) acc[G] = MFMA(A0[G][1][1], Bh1, acc[G]);
                #pragma unroll
                for (int G = 0; G < 4; ++G) acc[G] = MFMA(A0[G][2][0], Bxh, acc[G]);
                #pragma unroll
                for (int G = 0; G < 4; ++G) acc[G] = MFMA(A0[G][2][0], Bxl, acc[G]);
                #pragma unroll
                for (int G = 0; G < 4; ++G) acc[G] = MFMA(A0[G][2][1], Bxh, acc[G]);
                __builtin_amdgcn_s_setprio(0);

                float hv[4];
                #pragma unroll
                for (int j = 0; j < 4; ++j)
                    hv[j] = actstep(acc[0][j], acc[1][j], acc[2][j], acc[3][j], &cst[j]);
                unsigned hw0, lw0, hw1, lw1;
                packPair(hv[0], hv[1], &hw0, &lw0);
                packPair(hv[2], hv[3], &hw1, &lw1);
                *(uint2*)&h0hi[p^1][woff] = make_uint2(hw0, hw1);
                *(uint2*)&h0lo[p^1][woff] = make_uint2(lw0, lw1);

                if (doX) {
                    unsigned xw0, xl0, xw1, xl1;
                    packPair(xf.x, xf.y, &xw0, &xl0);
                    packPair(xf.z, xf.w, &xw1, &xl1);
                    xhi[p^1][lane*2+0] = xw0; xhi[p^1][lane*2+1] = xw1;
                    xlo[p^1][lane*2+0] = xl0; xlo[p^1][lane*2+1] = xl1;
                }
            }
            __syncthreads();
        }
    } else {
        // ======== LAYER 1 (1-step skew): iter i computes t=i-1 ========
        const int w = wv - 4;
        short8 A1[4][4][2];           // s=0,1: W_ih1 (vs h0); s=2,3: W_hh1 (vs h1)
        f32x4  bias4[4];
        #pragma unroll
        for (int G = 0; G < 4; ++G) {
            const int row = 64*G + 16*w + rl;
            #pragma unroll
            for (int s = 0; s < 4; ++s) {
                float w8[8];
                const float* src = (s < 2) ? (W_ih1 + row*64 + s*32 + g*8)
                                           : (W_hh1 + row*64 + (s-2)*32 + g*8);
                #pragma unroll
                for (int e = 0; e < 8; ++e) w8[e] = src[e];
                packA(w8, &A1[G][s][0], &A1[G][s][1]);
            }
            const int rb = 64*G + 16*w + 4*g;
            bias4[G].x = b_ih1[rb+0] + b_hh1[rb+0];
            bias4[G].y = b_ih1[rb+1] + b_hh1[rb+1];
            bias4[G].z = b_ih1[rb+2] + b_hh1[rb+2];
            bias4[G].w = b_ih1[rb+3] + b_hh1[rb+3];
        }
        float cst[4] = {0.f, 0.f, 0.f, 0.f};
        const int woff = w64off(rl, 8*w + 2*g);
        const int u0   = 16*w + 4*g;

        for (int i = 0; i <= TSEQ; ++i) {
            if (i > 0) {
                const int p = i & 1;
                short8 Bh[4], Bl[4];
                Bh[0] = ld128(h0hi[p], rl, 4*g);      Bl[0] = ld128(h0lo[p], rl, 4*g);
                Bh[1] = ld128(h0hi[p], rl, 16 + 4*g); Bl[1] = ld128(h0lo[p], rl, 16 + 4*g);
                Bh[2] = ld128(h1hi[p], rl, 4*g);      Bl[2] = ld128(h1lo[p], rl, 4*g);
                Bh[3] = ld128(h1hi[p], rl, 16 + 4*g); Bl[3] = ld128(h1lo[p], rl, 16 + 4*g);

                f32x4 acc[4];
                __builtin_amdgcn_s_setprio(1);
                #pragma unroll
                for (int G = 0; G < 4; ++G) acc[G] = MFMA(A1[G][0][0], Bh[0], bias4[G]);
                #pragma unroll
                for (int G = 0; G < 4; ++G) acc[G] = MFMA(A1[G][0][0], Bl[0], acc[G]);
                #pragma unroll
                for (int G = 0; G < 4; ++G) acc[G] = MFMA(A1[G][0][1], Bh[0], acc[G]);
                #pragma unroll
                for (int s = 1; s < 4; ++s) {
                    #pragma unroll
                    for (int G = 0; G < 4; ++G) acc[G] = MFMA(A1[G][s][0], Bh[s], acc[G]);
                    #pragma unroll
                    for (int G = 0; G < 4; ++G) acc[G] = MFMA(A1[G][s][0], Bl[s], acc[G]);
                    #pragma unroll
                    for (int G = 0; G < 4; ++G) acc[G] = MFMA(A1[G][s][1], Bh[s], acc[G]);
                }
                __builtin_amdgcn_s_setprio(0);

                float hv[4];
                #pragma unroll
                for (int j = 0; j < 4; ++j)
                    hv[j] = actstep(acc[0][j], acc[1][j], acc[2][j], acc[3][j], &cst[j]);
                unsigned hw0, lw0, hw1, lw1;
                packPair(hv[0], hv[1], &hw0, &lw0);
                packPair(hv[2], hv[3], &hw1, &lw1);
                *(uint2*)&h1hi[p^1][woff] = make_uint2(hw0, hw1);
                *(uint2*)&h1lo[p^1][woff] = make_uint2(lw0, lw1);

                if (i == TSEQ) {
                    #pragma unroll
                    for (int j = 0; j < 4; ++j) fcl[(u0 + j)*17 + rl] = hv[j];
                }
            }
            __syncthreads();
        }
    }

    // ---- FC: out[b] = h1_last[b,:] . W_fc + b_fc ----
    if (tid < 16) {
        float acc = b_fc[0];
        #pragma unroll 16
        for (int u = 0; u < 64; ++u) acc += fcl[u*17 + tid] * W_fc[u];
        out[b0 + tid] = acc;
    }
}

extern "C" void kernel_launch(void* const* d_in, const int* in_sizes, int n_in,
                              void* d_out, int out_size, void* d_ws, size_t ws_size,
                              hipStream_t stream) {
    const float* x     = (const float*)d_in[0];
    const float* W_ih0 = (const float*)d_in[1];
    const float* W_hh0 = (const float*)d_in[2];
    const float* b_ih0 = (const float*)d_in[3];
    const float* b_hh0 = (const float*)d_in[4];
    const float* W_ih1 = (const float*)d_in[5];
    const float* W_hh1 = (const float*)d_in[6];
    const float* b_ih1 = (const float*)d_in[7];
    const float* b_hh1 = (const float*)d_in[8];
    const float* W_fc  = (const float*)d_in[9];
    const float* b_fc  = (const float*)d_in[10];
    float* out = (float*)d_out;

    dim3 grid(4096 / 16), block(NTH);
    hipLaunchKernelGGL(lstm2_mfma, grid, block, 0, stream,
                       x, W_ih0, W_hh0, b_ih0, b_hh0,
                       W_ih1, W_hh1, b_ih1, b_hh1, W_fc, b_fc, out);
}